// Round 19
// baseline (281.138 us; speedup 1.0000x reference)
//
#include <hip/hip_runtime.h>
#include <hip/hip_fp16.h>

#define N_NODES   100000
#define N_EDGES   1600000
#define IN_CH     128
#define HID       64
#define N_CLASSES 16
#define N_GRAPHS  64

#define BK_SH     9                          // bucket = dst >> 9 (512 nodes/bucket)
#define BK_NODES  512
#define NB        ((N_NODES + BK_NODES - 1) / BK_NODES)   // 196 buckets
#define BK_CAP    10240                      // fixed bucket capacity (mean 8163, +23 sigma)
#define CH_EDGES  2048
#define EPT       8                          // edges/thread in binscatter (256 thr)
#define NCH       ((N_EDGES + CH_EDGES - 1) / CH_EDGES)   // 782 chunks
#define AGG_NPW   8                          // nodes per wave in aggregate

typedef __attribute__((ext_vector_type(8))) short bf16x8;
typedef __attribute__((ext_vector_type(4))) float f32x4;

__device__ __forceinline__ unsigned short f2bf(float f) {   // RNE f32->bf16
    unsigned u = __float_as_uint(f);
    u += 0x7fffu + ((u >> 16) & 1u);
    return (unsigned short)(u >> 16);
}
__device__ __forceinline__ float4 bf4(uint2 v) {            // 4 bf16 -> float4
    float4 o;
    o.x = __uint_as_float(v.x << 16);
    o.y = __uint_as_float(v.x & 0xffff0000u);
    o.z = __uint_as_float(v.y << 16);
    o.w = __uint_as_float(v.y & 0xffff0000u);
    return o;
}
// csr entry: src (17 bits) | fp16(ew) sign-free (15 bits) << 17
__device__ __forceinline__ float dec_ew(unsigned v) {
    return __half2float(__ushort_as_half((unsigned short)(v >> 17)));
}

// ---------------------------------------------------------------- init
__global__ void k_init(int* __restrict__ bcursor, float* __restrict__ pooled,
                       float* __restrict__ cnt) {
    int i = blockIdx.x * 256 + threadIdx.x;
    if (i < NB) bcursor[i] = i * BK_CAP;
    if (i < N_GRAPHS * HID) pooled[i] = 0.0f;
    if (i < N_GRAPHS) cnt[i] = 0.0f;
}

// ---------------------------------------------------------------- bin scatter
// Register-direct: hist pass assigns per-edge rank, one global atomic per
// (block,bucket) reserves the run, then edges written straight from registers.
// No LDS staging (51KB -> ~2.3KB), 8 waves/SIMD.
__global__ __launch_bounds__(256, 8) void k_binscatter(
        const int* __restrict__ src, const int* __restrict__ dst,
        const float* __restrict__ ew, int* __restrict__ bcursor,
        int2* __restrict__ bedges) {
    __shared__ int hist[NB];
    __shared__ int gbase[NB];
    const int t = threadIdx.x;
    const int base = blockIdx.x * CH_EDGES;

    for (int i = t; i < NB; i += 256) hist[i] = 0;
    __syncthreads();

    int myb[EPT], myr[EPT], myp[EPT]; float myw[EPT];
#pragma unroll
    for (int j = 0; j < EPT; ++j) {
        int i = base + j * 256 + t;
        if (i < N_EDGES) {
            int s = src[i], d = dst[i];
            int b = d >> BK_SH;
            myb[j] = b;
            myr[j] = atomicAdd(&hist[b], 1);
            myp[j] = s | ((d & (BK_NODES - 1)) << 17);
            myw[j] = ew[i];
        } else {
            myb[j] = -1;
        }
    }
    __syncthreads();

    if (t < NB) {
        int v = hist[t];
        gbase[t] = (v > 0) ? atomicAdd(&bcursor[t], v) : 0;
    }
    __syncthreads();

#pragma unroll
    for (int j = 0; j < EPT; ++j) {
        if (myb[j] >= 0)
            bedges[gbase[myb[j]] + myr[j]] =
                make_int2(myp[j], __float_as_int(myw[j]));
    }
}

// ---------------------------------------------------------------- build (fused)
__global__ __launch_bounds__(256) void k_build(const int* __restrict__ bcursor,
                                               const int2* __restrict__ bedges,
                                               int2* __restrict__ rowse,
                                               float* __restrict__ dis,
                                               unsigned* __restrict__ csr) {
    __shared__ int2  eds[BK_CAP];         // 80 KB
    __shared__ int   cnt[BK_NODES];
    __shared__ float dsum[BK_NODES];
    __shared__ int   cur[BK_NODES];
    __shared__ int   sc[256];
    const int b = blockIdx.x;
    const int t = threadIdx.x;
    const int beg = b * BK_CAP, end = bcursor[b];
    const int n = end - beg;

    for (int i = t; i < BK_NODES; i += 256) { cnt[i] = 0; dsum[i] = 0.0f; }
    __syncthreads();

    for (int i = t; i < n; i += 256) {
        int2 e = bedges[beg + i];
        eds[i] = e;
        int dl = ((unsigned)e.x) >> 17;
        atomicAdd(&cnt[dl], 1);
        atomicAdd(&dsum[dl], __int_as_float(e.y));
    }
    __syncthreads();

    int a0 = cnt[2 * t], a1 = cnt[2 * t + 1];
    int pair = a0 + a1;
    sc[t] = pair;
    __syncthreads();
    for (int off = 1; off < 256; off <<= 1) {
        int a = (t >= off) ? sc[t - off] : 0;
        __syncthreads();
        sc[t] += a;
        __syncthreads();
    }
    int excl = sc[t] - pair;
    cur[2 * t] = excl;
    cur[2 * t + 1] = excl + a0;
    {
        int n0 = b * BK_NODES + 2 * t;
        if (n0 < N_NODES) {
            rowse[n0] = make_int2(beg + excl, beg + excl + a0);
            dis[n0] = rsqrtf(1.0f + dsum[2 * t]);
        }
        int n1 = n0 + 1;
        if (n1 < N_NODES) {
            rowse[n1] = make_int2(beg + excl + a0, beg + excl + a0 + a1);
            dis[n1] = rsqrtf(1.0f + dsum[2 * t + 1]);
        }
    }
    __syncthreads();

    for (int i = t; i < n; i += 256) {
        int2 e = eds[i];
        int dl = ((unsigned)e.x) >> 17;
        int s = e.x & 0x1FFFF;
        unsigned short w16 = __half_as_ushort(__float2half(__int_as_float(e.y)));
        int pos = beg + atomicAdd(&cur[dl], 1);
        csr[pos] = (unsigned)s | ((unsigned)w16 << 17);
    }
}

// ---------------------------------------------------------------- GEMM via MFMA (f32 input)
// Epilogue scales by dis[row]: hb = bf16(dis * (x@W))  [norm factoring]
template <int K>
__global__ __launch_bounds__(256) void k_gemm(const float* __restrict__ x,
                                              const float* __restrict__ W,
                                              const float* __restrict__ dis,
                                              unsigned short* __restrict__ hb) {
    constexpr int AS = K + 8;            // padded stride in bf16 elems
    __shared__ unsigned short a_s[64 * AS];   // a_s[row][k]
    __shared__ unsigned short wt[64 * AS];    // wt[n][k] = W[k][n]
    const int t    = threadIdx.x;
    const int lane = t & 63;
    const int wave = t >> 6;
    const int m    = lane & 15;
    const int quad = lane >> 4;
    const int rowbase = blockIdx.x * 64;

    constexpr int CPR = K / 8;
    for (int c = t; c < 64 * CPR; c += 256) {
        int row = c / CPR, cc = c % CPR;
        int gr = rowbase + row;
        float4 v0, v1;
        if (gr < N_NODES) {
            v0 = *(const float4*)&x[(long)gr * K + cc * 8];
            v1 = *(const float4*)&x[(long)gr * K + cc * 8 + 4];
        } else {
            v0 = make_float4(0.f, 0.f, 0.f, 0.f); v1 = v0;
        }
        uint4 p;
        p.x = f2bf(v0.x) | ((unsigned)f2bf(v0.y) << 16);
        p.y = f2bf(v0.z) | ((unsigned)f2bf(v0.w) << 16);
        p.z = f2bf(v1.x) | ((unsigned)f2bf(v1.y) << 16);
        p.w = f2bf(v1.z) | ((unsigned)f2bf(v1.w) << 16);
        *(uint4*)&a_s[row * AS + cc * 8] = p;
    }
    for (int idx = t; idx < K * 64; idx += 256) {
        int k = idx >> 6, n = idx & 63;
        wt[n * AS + k] = f2bf(W[idx]);
    }
    __syncthreads();

    bf16x8 bfrag[4][K / 32];
#pragma unroll
    for (int nt = 0; nt < 4; ++nt)
#pragma unroll
        for (int ks = 0; ks < K / 32; ++ks)
            bfrag[nt][ks] = *(const bf16x8*)&wt[(nt * 16 + m) * AS + ks * 32 + quad * 8];

    f32x4 acc[4];
#pragma unroll
    for (int nt = 0; nt < 4; ++nt) acc[nt] = (f32x4){0.f, 0.f, 0.f, 0.f};

#pragma unroll
    for (int ks = 0; ks < K / 32; ++ks) {
        bf16x8 af = *(const bf16x8*)&a_s[(wave * 16 + m) * AS + ks * 32 + quad * 8];
#pragma unroll
        for (int nt = 0; nt < 4; ++nt)
            acc[nt] = __builtin_amdgcn_mfma_f32_16x16x32_bf16(af, bfrag[nt][ks],
                                                              acc[nt], 0, 0, 0);
    }

#pragma unroll
    for (int i = 0; i < 4; ++i) {
        int gr = rowbase + wave * 16 + quad * 4 + i;
        if (gr < N_NODES) {
            float dsc = dis[gr];
#pragma unroll
            for (int nt = 0; nt < 4; ++nt)
                hb[(long)gr * HID + nt * 16 + m] = f2bf(dsc * acc[nt][i]);
        }
    }
}

// ---------------------------------------------------------------- GEMM2 (bf16 input, K=64)
__global__ __launch_bounds__(256) void k_gemm2(const unsigned short* __restrict__ xb,
                                               const float* __restrict__ W,
                                               const float* __restrict__ dis,
                                               unsigned short* __restrict__ hb) {
    constexpr int K = HID;               // 64
    constexpr int AS = K + 8;            // 72
    __shared__ unsigned short a_s[64 * AS];
    __shared__ unsigned short wt[64 * AS];
    const int t    = threadIdx.x;
    const int lane = t & 63;
    const int wave = t >> 6;
    const int m    = lane & 15;
    const int quad = lane >> 4;
    const int rowbase = blockIdx.x * 64;

    // stage A: straight bf16 copy (8 uint4-chunks per row)
    for (int c = t; c < 64 * 8; c += 256) {
        int row = c >> 3, cc = c & 7;
        int gr = rowbase + row;
        uint4 p = (gr < N_NODES) ? *(const uint4*)&xb[(long)gr * K + cc * 8]
                                 : make_uint4(0, 0, 0, 0);
        *(uint4*)&a_s[row * AS + cc * 8] = p;
    }
    for (int idx = t; idx < K * 64; idx += 256) {
        int k = idx >> 6, n = idx & 63;
        wt[n * AS + k] = f2bf(W[idx]);
    }
    __syncthreads();

    bf16x8 bfrag[4][K / 32];
#pragma unroll
    for (int nt = 0; nt < 4; ++nt)
#pragma unroll
        for (int ks = 0; ks < K / 32; ++ks)
            bfrag[nt][ks] = *(const bf16x8*)&wt[(nt * 16 + m) * AS + ks * 32 + quad * 8];

    f32x4 acc[4];
#pragma unroll
    for (int nt = 0; nt < 4; ++nt) acc[nt] = (f32x4){0.f, 0.f, 0.f, 0.f};

#pragma unroll
    for (int ks = 0; ks < K / 32; ++ks) {
        bf16x8 af = *(const bf16x8*)&a_s[(wave * 16 + m) * AS + ks * 32 + quad * 8];
#pragma unroll
        for (int nt = 0; nt < 4; ++nt)
            acc[nt] = __builtin_amdgcn_mfma_f32_16x16x32_bf16(af, bfrag[nt][ks],
                                                              acc[nt], 0, 0, 0);
    }

#pragma unroll
    for (int i = 0; i < 4; ++i) {
        int gr = rowbase + wave * 16 + quad * 4 + i;
        if (gr < N_NODES) {
            float dsc = dis[gr];
#pragma unroll
            for (int nt = 0; nt < 4; ++nt)
                hb[(long)gr * HID + nt * 16 + m] = f2bf(dsc * acc[nt][i]);
        }
    }
}

// ---------------------------------------------------------------- aggregate (gather)
// Grid-stride AGG_NPW nodes/wave with rowse+self-row prefetch.
// OUT_BF16: epilogue writes bf16 rows (feeds gemm2 directly).
template <bool OUT_BF16>
__global__ void k_aggregate(const int2* __restrict__ rowse, const unsigned* __restrict__ csr,
                            const uint2* __restrict__ hb, const float* __restrict__ dis,
                            const float* __restrict__ b, float4* __restrict__ out4,
                            ushort4* __restrict__ outb) {
    const int tid  = threadIdx.x;
    const int lane = tid & 63;
    const int g    = lane >> 4;          // edge group 0..3
    const int c4   = lane & 15;          // channel quad index
    const int nodebase = (blockIdx.x * 4 + (tid >> 6)) * AGG_NPW;
    const float4 bb = ((const float4*)b)[c4];

    if (nodebase >= N_NODES) return;

    int2 rs = rowse[nodebase];
    uint2 hsr = hb[nodebase * 16 + c4];

    for (int j = 0; j < AGG_NPW; ++j) {
        const int node = nodebase + j;
        if (node >= N_NODES) return;

        const int2 rs_c = rs;
        const float4 hs = bf4(hsr);
        if (j + 1 < AGG_NPW && node + 1 < N_NODES) {
            rs  = rowse[node + 1];
            hsr = hb[(node + 1) * 16 + c4];
        }

        float4 acc;
        if (g == 0) { acc = hs; }
        else        { acc.x = 0.f; acc.y = 0.f; acc.z = 0.f; acc.w = 0.f; }

        int p = rs_c.x;
        const int end = rs_c.y;

        unsigned d0, d1, d2, d3;
        if (p + 16 <= end) {
            d0 = csr[p + g];     d1 = csr[p + 4 + g];
            d2 = csr[p + 8 + g]; d3 = csr[p + 12 + g];
        }
        while (p + 16 <= end) {
            const unsigned e0 = d0, e1 = d1, e2 = d2, e3 = d3;
            const int pn = p + 16;
            if (pn + 16 <= end) {
                d0 = csr[pn + g];     d1 = csr[pn + 4 + g];
                d2 = csr[pn + 8 + g]; d3 = csr[pn + 12 + g];
            }
            float4 v0 = bf4(hb[(e0 & 0x1FFFF) * 16 + c4]);
            float4 v1 = bf4(hb[(e1 & 0x1FFFF) * 16 + c4]);
            float4 v2 = bf4(hb[(e2 & 0x1FFFF) * 16 + c4]);
            float4 v3 = bf4(hb[(e3 & 0x1FFFF) * 16 + c4]);
            float w0 = dec_ew(e0), w1 = dec_ew(e1);
            float w2 = dec_ew(e2), w3 = dec_ew(e3);
            acc.x += w0 * v0.x; acc.y += w0 * v0.y; acc.z += w0 * v0.z; acc.w += w0 * v0.w;
            acc.x += w1 * v1.x; acc.y += w1 * v1.y; acc.z += w1 * v1.z; acc.w += w1 * v1.w;
            acc.x += w2 * v2.x; acc.y += w2 * v2.y; acc.z += w2 * v2.z; acc.w += w2 * v2.w;
            acc.x += w3 * v3.x; acc.y += w3 * v3.y; acc.z += w3 * v3.z; acc.w += w3 * v3.w;
            p = pn;
        }
        if (p < end) {   // clamped tail block
            int i0 = p + g, i1 = p + 4 + g, i2 = p + 8 + g, i3 = p + 12 + g;
            unsigned e0 = csr[min(i0, end - 1)];
            unsigned e1 = csr[min(i1, end - 1)];
            unsigned e2 = csr[min(i2, end - 1)];
            unsigned e3 = csr[min(i3, end - 1)];
            float4 v0 = bf4(hb[(e0 & 0x1FFFF) * 16 + c4]);
            float4 v1 = bf4(hb[(e1 & 0x1FFFF) * 16 + c4]);
            float4 v2 = bf4(hb[(e2 & 0x1FFFF) * 16 + c4]);
            float4 v3 = bf4(hb[(e3 & 0x1FFFF) * 16 + c4]);
            float w0 = (i0 < end) ? dec_ew(e0) : 0.0f;
            float w1 = (i1 < end) ? dec_ew(e1) : 0.0f;
            float w2 = (i2 < end) ? dec_ew(e2) : 0.0f;
            float w3 = (i3 < end) ? dec_ew(e3) : 0.0f;
            acc.x += w0 * v0.x; acc.y += w0 * v0.y; acc.z += w0 * v0.z; acc.w += w0 * v0.w;
            acc.x += w1 * v1.x; acc.y += w1 * v1.y; acc.z += w1 * v1.z; acc.w += w1 * v1.w;
            acc.x += w2 * v2.x; acc.y += w2 * v2.y; acc.z += w2 * v2.z; acc.w += w2 * v2.w;
            acc.x += w3 * v3.x; acc.y += w3 * v3.y; acc.z += w3 * v3.z; acc.w += w3 * v3.w;
        }

        acc.x += __shfl_xor(acc.x, 16); acc.y += __shfl_xor(acc.y, 16);
        acc.z += __shfl_xor(acc.z, 16); acc.w += __shfl_xor(acc.w, 16);
        acc.x += __shfl_xor(acc.x, 32); acc.y += __shfl_xor(acc.y, 32);
        acc.z += __shfl_xor(acc.z, 32); acc.w += __shfl_xor(acc.w, 32);

        if (g == 0) {
            const float dd = dis[node];
            float4 o;
            o.x = fmaxf(dd * acc.x + bb.x, 0.0f);
            o.y = fmaxf(dd * acc.y + bb.y, 0.0f);
            o.z = fmaxf(dd * acc.z + bb.z, 0.0f);
            o.w = fmaxf(dd * acc.w + bb.w, 0.0f);
            if (OUT_BF16) {
                ushort4 ob;
                ob.x = f2bf(o.x); ob.y = f2bf(o.y);
                ob.z = f2bf(o.z); ob.w = f2bf(o.w);
                outb[node * 16 + c4] = ob;
            } else {
                out4[node * 16 + c4] = o;
            }
        }
    }
}

// ---------------------------------------------------------------- pool (hierarchical)
#define POOL_NPB 256   // nodes per 1024-thread block
__global__ __launch_bounds__(1024) void k_pool(const float* __restrict__ agg,
                                               const int* __restrict__ batch,
                                               float* __restrict__ pooled,
                                               float* __restrict__ cnt) {
    __shared__ float psh[N_GRAPHS * HID];   // 16 KB
    __shared__ float csh[N_GRAPHS];
    const int tid = threadIdx.x;
    const int c = tid & 63;
    const int w = tid >> 6;                 // wave 0..15
    const int nodebase = blockIdx.x * POOL_NPB + w * 16;

    for (int i = tid; i < N_GRAPHS * HID; i += 1024) psh[i] = 0.f;
    if (tid < N_GRAPHS) csh[tid] = 0.f;
    __syncthreads();

    int curg = -1; float accv = 0.f, cntacc = 0.f;
    for (int j = 0; j < 16; ++j) {
        int node = nodebase + j;
        if (node >= N_NODES) break;
        int g = batch[node];                // wave-uniform
        float v = agg[node * HID + c];
        if (g != curg) {
            if (curg >= 0) {
                atomicAdd(&psh[curg * HID + c], accv);
                if (c == 0) atomicAdd(&csh[curg], cntacc);
            }
            curg = g; accv = 0.f; cntacc = 0.f;
        }
        accv += v; cntacc += 1.f;
    }
    if (curg >= 0) {
        atomicAdd(&psh[curg * HID + c], accv);
        if (c == 0) atomicAdd(&csh[curg], cntacc);
    }
    __syncthreads();

    for (int i = tid; i < N_GRAPHS * HID; i += 1024) {
        if (csh[i >> 6] > 0.f) atomicAdd(&pooled[i], psh[i]);
    }
    if (tid < N_GRAPHS && csh[tid] > 0.f) atomicAdd(&cnt[tid], csh[tid]);
}

// ---------------------------------------------------------------- head
__global__ void k_out(const float* __restrict__ pooled, const float* __restrict__ cnt,
                      const float* __restrict__ Wl, const float* __restrict__ bl,
                      float* __restrict__ out) {
    int tid = threadIdx.x;              // 1024 threads
    int g = tid >> 4, k = tid & 15;
    float inv = 1.0f / fmaxf(cnt[g], 1.0f);
    float acc = 0.f;
#pragma unroll
    for (int h = 0; h < HID; ++h) acc += pooled[g * HID + h] * Wl[h * N_CLASSES + k];
    out[g * N_CLASSES + k] = acc * inv + bl[k];
}

extern "C" void kernel_launch(void* const* d_in, const int* in_sizes, int n_in,
                              void* d_out, int out_size, void* d_ws, size_t ws_size,
                              hipStream_t stream) {
    const float* x     = (const float*)d_in[0];
    const int*   ei    = (const int*)d_in[1];
    const float* ew    = (const float*)d_in[2];
    const int*   batch = (const int*)d_in[3];
    const float* W1    = (const float*)d_in[4];
    const float* b1    = (const float*)d_in[5];
    const float* W2    = (const float*)d_in[6];
    const float* b2    = (const float*)d_in[7];
    const float* Wl    = (const float*)d_in[8];
    const float* bl    = (const float*)d_in[9];

    const int* srcv = ei;            // edge_index[0]
    const int* dstv = ei + N_EDGES;  // edge_index[1]

    // workspace layout (all offsets 16B-aligned)
    char* wsb = (char*)d_ws;
    float*          dis    = (float*)wsb;              wsb += 100352 * 4;
    int2*           rowse  = (int2*)wsb;               wsb += 100352 * 8;   // {beg,end}/node
    int*            bcursor= (int*)wsb;                wsb += 256 * 4;
    unsigned*       csr    = (unsigned*)wsb;           wsb += (size_t)NB * BK_CAP * 4;
    unsigned short* hb     = (unsigned short*)wsb;     wsb += N_NODES * HID * 2;  // bf16 dis*h
    unsigned short* hbn    = (unsigned short*)wsb;     wsb += N_NODES * HID * 2;  // bf16 h1
    float*          agg    = (float*)wsb;              wsb += N_NODES * HID * 4;
    float*          pooled = (float*)wsb;              wsb += N_GRAPHS * HID * 4;
    float*          cnt    = (float*)wsb;              wsb += N_GRAPHS * 4;
    float*          out    = (float*)d_out;
    int2*           bedges = (int2*)agg;  // aliases agg; consumed in k_build before aggregate2

    // ---- CSR build (counting sort, fixed-capacity buckets, fused build)
    k_init<<<16, 256, 0, stream>>>(bcursor, pooled, cnt);
    k_binscatter<<<NCH, 256, 0, stream>>>(srcv, dstv, ew, bcursor, bedges);
    k_build<<<NB, 256, 0, stream>>>(bcursor, bedges, rowse, dis, csr);

    const int agg_blocks = (N_NODES + 4 * AGG_NPW - 1) / (4 * AGG_NPW);

    // ---- layer 1 (aggregate writes bf16 -> feeds gemm2 directly)
    k_gemm<IN_CH><<<(N_NODES + 63) / 64, 256, 0, stream>>>(x, W1, dis, hb);
    k_aggregate<true><<<agg_blocks, 256, 0, stream>>>(rowse, csr, (const uint2*)hb,
                                                      dis, b1, nullptr, (ushort4*)hbn);
    // ---- layer 2
    k_gemm2<<<(N_NODES + 63) / 64, 256, 0, stream>>>(hbn, W2, dis, hb);
    k_aggregate<false><<<agg_blocks, 256, 0, stream>>>(rowse, csr, (const uint2*)hb,
                                                       dis, b2, (float4*)agg, nullptr);

    // ---- pool + head
    k_pool<<<(N_NODES + POOL_NPB - 1) / POOL_NPB, 1024, 0, stream>>>(
        agg, batch, pooled, cnt);
    k_out<<<1, N_GRAPHS * N_CLASSES, 0, stream>>>(pooled, cnt, Wl, bl, out);
}

// Round 20
// 275.181 us; speedup vs baseline: 1.0216x; 1.0216x over previous
//
#include <hip/hip_runtime.h>
#include <hip/hip_fp16.h>

#define N_NODES   100000
#define N_EDGES   1600000
#define IN_CH     128
#define HID       64
#define N_CLASSES 16
#define N_GRAPHS  64

#define BK_SH     9                          // bucket = dst >> 9 (512 nodes/bucket)
#define BK_NODES  512
#define NB        ((N_NODES + BK_NODES - 1) / BK_NODES)   // 196 buckets
#define BK_CAP    10240                      // fixed bucket capacity (mean 8163, +23 sigma)
#define CH_EDGES  4096
#define EPT       16                         // edges/thread in binscatter (256 thr)
#define NCH       ((N_EDGES + CH_EDGES - 1) / CH_EDGES)   // 391 chunks
#define AGG_NPW   8                          // nodes per wave in aggregate

typedef __attribute__((ext_vector_type(8))) short bf16x8;
typedef __attribute__((ext_vector_type(4))) float f32x4;

__device__ __forceinline__ unsigned short f2bf(float f) {   // RNE f32->bf16
    unsigned u = __float_as_uint(f);
    u += 0x7fffu + ((u >> 16) & 1u);
    return (unsigned short)(u >> 16);
}
__device__ __forceinline__ float4 bf4(uint2 v) {            // 4 bf16 -> float4
    float4 o;
    o.x = __uint_as_float(v.x << 16);
    o.y = __uint_as_float(v.x & 0xffff0000u);
    o.z = __uint_as_float(v.y << 16);
    o.w = __uint_as_float(v.y & 0xffff0000u);
    return o;
}
// csr entry: src (17 bits) | fp16(ew) sign-free (15 bits) << 17
__device__ __forceinline__ float dec_ew(unsigned v) {
    return __half2float(__ushort_as_half((unsigned short)(v >> 17)));
}

// ---------------------------------------------------------------- init
__global__ void k_init(int* __restrict__ bcursor, float* __restrict__ pooled,
                       float* __restrict__ cnt) {
    int i = blockIdx.x * 256 + threadIdx.x;
    if (i < NB) bcursor[i] = i * BK_CAP;
    if (i < N_GRAPHS * HID) pooled[i] = 0.0f;
    if (i < N_GRAPHS) cnt[i] = 0.0f;
}

// ---------------------------------------------------------------- bin scatter (staged)
// LDS-sorted staging -> contiguous run writes. Measured better than the
// register-direct variant (R19: +11 us) despite 51 KB LDS.
__global__ void k_binscatter(const int* __restrict__ src, const int* __restrict__ dst,
                             const float* __restrict__ ew, int* __restrict__ bcursor,
                             int2* __restrict__ bedges) {
    __shared__ int  hist[NB];
    __shared__ int  offs[NB];
    __shared__ int  gbase[NB];
    __shared__ int  sc[256];
    __shared__ int2 stage[CH_EDGES];
    __shared__ int  dest[CH_EDGES];
    const int t = threadIdx.x;
    const int base = blockIdx.x * CH_EDGES;
    const int nloc = min(CH_EDGES, N_EDGES - base);

    for (int i = t; i < NB; i += 256) hist[i] = 0;
    __syncthreads();

    int myb[EPT], myr[EPT], myp[EPT]; float myw[EPT];
#pragma unroll
    for (int j = 0; j < EPT; ++j) {
        int i = base + j * 256 + t;
        if (i < N_EDGES) {
            int s = src[i], d = dst[i];
            int b = d >> BK_SH;
            myb[j] = b;
            myr[j] = atomicAdd(&hist[b], 1);
            myp[j] = s | ((d & (BK_NODES - 1)) << 17);
            myw[j] = ew[i];
        } else {
            myb[j] = -1;
        }
    }
    __syncthreads();

    int v = (t < NB) ? hist[t] : 0;
    sc[t] = v;
    __syncthreads();
    for (int off = 1; off < 256; off <<= 1) {
        int a = (t >= off) ? sc[t - off] : 0;
        __syncthreads();
        sc[t] += a;
        __syncthreads();
    }
    if (t < NB) {
        offs[t] = sc[t] - v;
        gbase[t] = (v > 0) ? atomicAdd(&bcursor[t], v) : 0;
    }
    __syncthreads();

#pragma unroll
    for (int j = 0; j < EPT; ++j) {
        if (myb[j] >= 0) {
            int p = offs[myb[j]] + myr[j];
            stage[p] = make_int2(myp[j], __float_as_int(myw[j]));
            dest[p] = gbase[myb[j]] + myr[j];
        }
    }
    __syncthreads();

    for (int i = t; i < nloc; i += 256)
        bedges[dest[i]] = stage[i];
}

// ---------------------------------------------------------------- build (fused)
__global__ __launch_bounds__(256) void k_build(const int* __restrict__ bcursor,
                                               const int2* __restrict__ bedges,
                                               int2* __restrict__ rowse,
                                               float* __restrict__ dis,
                                               unsigned* __restrict__ csr) {
    __shared__ int2  eds[BK_CAP];         // 80 KB
    __shared__ int   cnt[BK_NODES];
    __shared__ float dsum[BK_NODES];
    __shared__ int   cur[BK_NODES];
    __shared__ int   sc[256];
    const int b = blockIdx.x;
    const int t = threadIdx.x;
    const int beg = b * BK_CAP, end = bcursor[b];
    const int n = end - beg;

    for (int i = t; i < BK_NODES; i += 256) { cnt[i] = 0; dsum[i] = 0.0f; }
    __syncthreads();

    for (int i = t; i < n; i += 256) {
        int2 e = bedges[beg + i];
        eds[i] = e;
        int dl = ((unsigned)e.x) >> 17;
        atomicAdd(&cnt[dl], 1);
        atomicAdd(&dsum[dl], __int_as_float(e.y));
    }
    __syncthreads();

    int a0 = cnt[2 * t], a1 = cnt[2 * t + 1];
    int pair = a0 + a1;
    sc[t] = pair;
    __syncthreads();
    for (int off = 1; off < 256; off <<= 1) {
        int a = (t >= off) ? sc[t - off] : 0;
        __syncthreads();
        sc[t] += a;
        __syncthreads();
    }
    int excl = sc[t] - pair;
    cur[2 * t] = excl;
    cur[2 * t + 1] = excl + a0;
    {
        int n0 = b * BK_NODES + 2 * t;
        if (n0 < N_NODES) {
            rowse[n0] = make_int2(beg + excl, beg + excl + a0);
            dis[n0] = rsqrtf(1.0f + dsum[2 * t]);
        }
        int n1 = n0 + 1;
        if (n1 < N_NODES) {
            rowse[n1] = make_int2(beg + excl + a0, beg + excl + a0 + a1);
            dis[n1] = rsqrtf(1.0f + dsum[2 * t + 1]);
        }
    }
    __syncthreads();

    for (int i = t; i < n; i += 256) {
        int2 e = eds[i];
        int dl = ((unsigned)e.x) >> 17;
        int s = e.x & 0x1FFFF;
        unsigned short w16 = __half_as_ushort(__float2half(__int_as_float(e.y)));
        int pos = beg + atomicAdd(&cur[dl], 1);
        csr[pos] = (unsigned)s | ((unsigned)w16 << 17);
    }
}

// ---------------------------------------------------------------- GEMM via MFMA (f32 input)
// Epilogue scales by dis[row]: hb = bf16(dis * (x@W))  [norm factoring]
template <int K>
__global__ __launch_bounds__(256) void k_gemm(const float* __restrict__ x,
                                              const float* __restrict__ W,
                                              const float* __restrict__ dis,
                                              unsigned short* __restrict__ hb) {
    constexpr int AS = K + 8;            // padded stride in bf16 elems
    __shared__ unsigned short a_s[64 * AS];   // a_s[row][k]
    __shared__ unsigned short wt[64 * AS];    // wt[n][k] = W[k][n]
    const int t    = threadIdx.x;
    const int lane = t & 63;
    const int wave = t >> 6;
    const int m    = lane & 15;
    const int quad = lane >> 4;
    const int rowbase = blockIdx.x * 64;

    constexpr int CPR = K / 8;
    for (int c = t; c < 64 * CPR; c += 256) {
        int row = c / CPR, cc = c % CPR;
        int gr = rowbase + row;
        float4 v0, v1;
        if (gr < N_NODES) {
            v0 = *(const float4*)&x[(long)gr * K + cc * 8];
            v1 = *(const float4*)&x[(long)gr * K + cc * 8 + 4];
        } else {
            v0 = make_float4(0.f, 0.f, 0.f, 0.f); v1 = v0;
        }
        uint4 p;
        p.x = f2bf(v0.x) | ((unsigned)f2bf(v0.y) << 16);
        p.y = f2bf(v0.z) | ((unsigned)f2bf(v0.w) << 16);
        p.z = f2bf(v1.x) | ((unsigned)f2bf(v1.y) << 16);
        p.w = f2bf(v1.z) | ((unsigned)f2bf(v1.w) << 16);
        *(uint4*)&a_s[row * AS + cc * 8] = p;
    }
    for (int idx = t; idx < K * 64; idx += 256) {
        int k = idx >> 6, n = idx & 63;
        wt[n * AS + k] = f2bf(W[idx]);
    }
    __syncthreads();

    bf16x8 bfrag[4][K / 32];
#pragma unroll
    for (int nt = 0; nt < 4; ++nt)
#pragma unroll
        for (int ks = 0; ks < K / 32; ++ks)
            bfrag[nt][ks] = *(const bf16x8*)&wt[(nt * 16 + m) * AS + ks * 32 + quad * 8];

    f32x4 acc[4];
#pragma unroll
    for (int nt = 0; nt < 4; ++nt) acc[nt] = (f32x4){0.f, 0.f, 0.f, 0.f};

#pragma unroll
    for (int ks = 0; ks < K / 32; ++ks) {
        bf16x8 af = *(const bf16x8*)&a_s[(wave * 16 + m) * AS + ks * 32 + quad * 8];
#pragma unroll
        for (int nt = 0; nt < 4; ++nt)
            acc[nt] = __builtin_amdgcn_mfma_f32_16x16x32_bf16(af, bfrag[nt][ks],
                                                              acc[nt], 0, 0, 0);
    }

#pragma unroll
    for (int i = 0; i < 4; ++i) {
        int gr = rowbase + wave * 16 + quad * 4 + i;
        if (gr < N_NODES) {
            float dsc = dis[gr];
#pragma unroll
            for (int nt = 0; nt < 4; ++nt)
                hb[(long)gr * HID + nt * 16 + m] = f2bf(dsc * acc[nt][i]);
        }
    }
}

// ---------------------------------------------------------------- GEMM2 (bf16 input, K=64)
__global__ __launch_bounds__(256) void k_gemm2(const unsigned short* __restrict__ xb,
                                               const float* __restrict__ W,
                                               const float* __restrict__ dis,
                                               unsigned short* __restrict__ hb) {
    constexpr int K = HID;               // 64
    constexpr int AS = K + 8;            // 72
    __shared__ unsigned short a_s[64 * AS];
    __shared__ unsigned short wt[64 * AS];
    const int t    = threadIdx.x;
    const int lane = t & 63;
    const int wave = t >> 6;
    const int m    = lane & 15;
    const int quad = lane >> 4;
    const int rowbase = blockIdx.x * 64;

    for (int c = t; c < 64 * 8; c += 256) {
        int row = c >> 3, cc = c & 7;
        int gr = rowbase + row;
        uint4 p = (gr < N_NODES) ? *(const uint4*)&xb[(long)gr * K + cc * 8]
                                 : make_uint4(0, 0, 0, 0);
        *(uint4*)&a_s[row * AS + cc * 8] = p;
    }
    for (int idx = t; idx < K * 64; idx += 256) {
        int k = idx >> 6, n = idx & 63;
        wt[n * AS + k] = f2bf(W[idx]);
    }
    __syncthreads();

    bf16x8 bfrag[4][K / 32];
#pragma unroll
    for (int nt = 0; nt < 4; ++nt)
#pragma unroll
        for (int ks = 0; ks < K / 32; ++ks)
            bfrag[nt][ks] = *(const bf16x8*)&wt[(nt * 16 + m) * AS + ks * 32 + quad * 8];

    f32x4 acc[4];
#pragma unroll
    for (int nt = 0; nt < 4; ++nt) acc[nt] = (f32x4){0.f, 0.f, 0.f, 0.f};

#pragma unroll
    for (int ks = 0; ks < K / 32; ++ks) {
        bf16x8 af = *(const bf16x8*)&a_s[(wave * 16 + m) * AS + ks * 32 + quad * 8];
#pragma unroll
        for (int nt = 0; nt < 4; ++nt)
            acc[nt] = __builtin_amdgcn_mfma_f32_16x16x32_bf16(af, bfrag[nt][ks],
                                                              acc[nt], 0, 0, 0);
    }

#pragma unroll
    for (int i = 0; i < 4; ++i) {
        int gr = rowbase + wave * 16 + quad * 4 + i;
        if (gr < N_NODES) {
            float dsc = dis[gr];
#pragma unroll
            for (int nt = 0; nt < 4; ++nt)
                hb[(long)gr * HID + nt * 16 + m] = f2bf(dsc * acc[nt][i]);
        }
    }
}

// ---------------------------------------------------------------- aggregate (gather)
template <bool OUT_BF16>
__global__ void k_aggregate(const int2* __restrict__ rowse, const unsigned* __restrict__ csr,
                            const uint2* __restrict__ hb, const float* __restrict__ dis,
                            const float* __restrict__ b, float4* __restrict__ out4,
                            ushort4* __restrict__ outb) {
    const int tid  = threadIdx.x;
    const int lane = tid & 63;
    const int g    = lane >> 4;          // edge group 0..3
    const int c4   = lane & 15;          // channel quad index
    const int nodebase = (blockIdx.x * 4 + (tid >> 6)) * AGG_NPW;
    const float4 bb = ((const float4*)b)[c4];

    if (nodebase >= N_NODES) return;

    int2 rs = rowse[nodebase];
    uint2 hsr = hb[nodebase * 16 + c4];

    for (int j = 0; j < AGG_NPW; ++j) {
        const int node = nodebase + j;
        if (node >= N_NODES) return;

        const int2 rs_c = rs;
        const float4 hs = bf4(hsr);
        if (j + 1 < AGG_NPW && node + 1 < N_NODES) {
            rs  = rowse[node + 1];
            hsr = hb[(node + 1) * 16 + c4];
        }

        float4 acc;
        if (g == 0) { acc = hs; }
        else        { acc.x = 0.f; acc.y = 0.f; acc.z = 0.f; acc.w = 0.f; }

        int p = rs_c.x;
        const int end = rs_c.y;

        unsigned d0, d1, d2, d3;
        if (p + 16 <= end) {
            d0 = csr[p + g];     d1 = csr[p + 4 + g];
            d2 = csr[p + 8 + g]; d3 = csr[p + 12 + g];
        }
        while (p + 16 <= end) {
            const unsigned e0 = d0, e1 = d1, e2 = d2, e3 = d3;
            const int pn = p + 16;
            if (pn + 16 <= end) {
                d0 = csr[pn + g];     d1 = csr[pn + 4 + g];
                d2 = csr[pn + 8 + g]; d3 = csr[pn + 12 + g];
            }
            float4 v0 = bf4(hb[(e0 & 0x1FFFF) * 16 + c4]);
            float4 v1 = bf4(hb[(e1 & 0x1FFFF) * 16 + c4]);
            float4 v2 = bf4(hb[(e2 & 0x1FFFF) * 16 + c4]);
            float4 v3 = bf4(hb[(e3 & 0x1FFFF) * 16 + c4]);
            float w0 = dec_ew(e0), w1 = dec_ew(e1);
            float w2 = dec_ew(e2), w3 = dec_ew(e3);
            acc.x += w0 * v0.x; acc.y += w0 * v0.y; acc.z += w0 * v0.z; acc.w += w0 * v0.w;
            acc.x += w1 * v1.x; acc.y += w1 * v1.y; acc.z += w1 * v1.z; acc.w += w1 * v1.w;
            acc.x += w2 * v2.x; acc.y += w2 * v2.y; acc.z += w2 * v2.z; acc.w += w2 * v2.w;
            acc.x += w3 * v3.x; acc.y += w3 * v3.y; acc.z += w3 * v3.z; acc.w += w3 * v3.w;
            p = pn;
        }
        if (p < end) {   // clamped tail block
            int i0 = p + g, i1 = p + 4 + g, i2 = p + 8 + g, i3 = p + 12 + g;
            unsigned e0 = csr[min(i0, end - 1)];
            unsigned e1 = csr[min(i1, end - 1)];
            unsigned e2 = csr[min(i2, end - 1)];
            unsigned e3 = csr[min(i3, end - 1)];
            float4 v0 = bf4(hb[(e0 & 0x1FFFF) * 16 + c4]);
            float4 v1 = bf4(hb[(e1 & 0x1FFFF) * 16 + c4]);
            float4 v2 = bf4(hb[(e2 & 0x1FFFF) * 16 + c4]);
            float4 v3 = bf4(hb[(e3 & 0x1FFFF) * 16 + c4]);
            float w0 = (i0 < end) ? dec_ew(e0) : 0.0f;
            float w1 = (i1 < end) ? dec_ew(e1) : 0.0f;
            float w2 = (i2 < end) ? dec_ew(e2) : 0.0f;
            float w3 = (i3 < end) ? dec_ew(e3) : 0.0f;
            acc.x += w0 * v0.x; acc.y += w0 * v0.y; acc.z += w0 * v0.z; acc.w += w0 * v0.w;
            acc.x += w1 * v1.x; acc.y += w1 * v1.y; acc.z += w1 * v1.z; acc.w += w1 * v1.w;
            acc.x += w2 * v2.x; acc.y += w2 * v2.y; acc.z += w2 * v2.z; acc.w += w2 * v2.w;
            acc.x += w3 * v3.x; acc.y += w3 * v3.y; acc.z += w3 * v3.z; acc.w += w3 * v3.w;
        }

        acc.x += __shfl_xor(acc.x, 16); acc.y += __shfl_xor(acc.y, 16);
        acc.z += __shfl_xor(acc.z, 16); acc.w += __shfl_xor(acc.w, 16);
        acc.x += __shfl_xor(acc.x, 32); acc.y += __shfl_xor(acc.y, 32);
        acc.z += __shfl_xor(acc.z, 32); acc.w += __shfl_xor(acc.w, 32);

        if (g == 0) {
            const float dd = dis[node];
            float4 o;
            o.x = fmaxf(dd * acc.x + bb.x, 0.0f);
            o.y = fmaxf(dd * acc.y + bb.y, 0.0f);
            o.z = fmaxf(dd * acc.z + bb.z, 0.0f);
            o.w = fmaxf(dd * acc.w + bb.w, 0.0f);
            if (OUT_BF16) {
                ushort4 ob;
                ob.x = f2bf(o.x); ob.y = f2bf(o.y);
                ob.z = f2bf(o.z); ob.w = f2bf(o.w);
                outb[node * 16 + c4] = ob;
            } else {
                out4[node * 16 + c4] = o;
            }
        }
    }
}

// ---------------------------------------------------------------- pool (hierarchical)
#define POOL_NPB 256   // nodes per 1024-thread block
__global__ __launch_bounds__(1024) void k_pool(const float* __restrict__ agg,
                                               const int* __restrict__ batch,
                                               float* __restrict__ pooled,
                                               float* __restrict__ cnt) {
    __shared__ float psh[N_GRAPHS * HID];   // 16 KB
    __shared__ float csh[N_GRAPHS];
    const int tid = threadIdx.x;
    const int c = tid & 63;
    const int w = tid >> 6;                 // wave 0..15
    const int nodebase = blockIdx.x * POOL_NPB + w * 16;

    for (int i = tid; i < N_GRAPHS * HID; i += 1024) psh[i] = 0.f;
    if (tid < N_GRAPHS) csh[tid] = 0.f;
    __syncthreads();

    int curg = -1; float accv = 0.f, cntacc = 0.f;
    for (int j = 0; j < 16; ++j) {
        int node = nodebase + j;
        if (node >= N_NODES) break;
        int g = batch[node];                // wave-uniform
        float v = agg[node * HID + c];
        if (g != curg) {
            if (curg >= 0) {
                atomicAdd(&psh[curg * HID + c], accv);
                if (c == 0) atomicAdd(&csh[curg], cntacc);
            }
            curg = g; accv = 0.f; cntacc = 0.f;
        }
        accv += v; cntacc += 1.f;
    }
    if (curg >= 0) {
        atomicAdd(&psh[curg * HID + c], accv);
        if (c == 0) atomicAdd(&csh[curg], cntacc);
    }
    __syncthreads();

    for (int i = tid; i < N_GRAPHS * HID; i += 1024) {
        if (csh[i >> 6] > 0.f) atomicAdd(&pooled[i], psh[i]);
    }
    if (tid < N_GRAPHS && csh[tid] > 0.f) atomicAdd(&cnt[tid], csh[tid]);
}

// ---------------------------------------------------------------- head
__global__ void k_out(const float* __restrict__ pooled, const float* __restrict__ cnt,
                      const float* __restrict__ Wl, const float* __restrict__ bl,
                      float* __restrict__ out) {
    int tid = threadIdx.x;              // 1024 threads
    int g = tid >> 4, k = tid & 15;
    float inv = 1.0f / fmaxf(cnt[g], 1.0f);
    float acc = 0.f;
#pragma unroll
    for (int h = 0; h < HID; ++h) acc += pooled[g * HID + h] * Wl[h * N_CLASSES + k];
    out[g * N_CLASSES + k] = acc * inv + bl[k];
}

extern "C" void kernel_launch(void* const* d_in, const int* in_sizes, int n_in,
                              void* d_out, int out_size, void* d_ws, size_t ws_size,
                              hipStream_t stream) {
    const float* x     = (const float*)d_in[0];
    const int*   ei    = (const int*)d_in[1];
    const float* ew    = (const float*)d_in[2];
    const int*   batch = (const int*)d_in[3];
    const float* W1    = (const float*)d_in[4];
    const float* b1    = (const float*)d_in[5];
    const float* W2    = (const float*)d_in[6];
    const float* b2    = (const float*)d_in[7];
    const float* Wl    = (const float*)d_in[8];
    const float* bl    = (const float*)d_in[9];

    const int* srcv = ei;            // edge_index[0]
    const int* dstv = ei + N_EDGES;  // edge_index[1]

    // workspace layout (all offsets 16B-aligned)
    char* wsb = (char*)d_ws;
    float*          dis    = (float*)wsb;              wsb += 100352 * 4;
    int2*           rowse  = (int2*)wsb;               wsb += 100352 * 8;   // {beg,end}/node
    int*            bcursor= (int*)wsb;                wsb += 256 * 4;
    unsigned*       csr    = (unsigned*)wsb;           wsb += (size_t)NB * BK_CAP * 4;
    unsigned short* hb     = (unsigned short*)wsb;     wsb += N_NODES * HID * 2;  // bf16 dis*h
    unsigned short* hbn    = (unsigned short*)wsb;     wsb += N_NODES * HID * 2;  // bf16 h1
    float*          agg    = (float*)wsb;              wsb += N_NODES * HID * 4;
    float*          pooled = (float*)wsb;              wsb += N_GRAPHS * HID * 4;
    float*          cnt    = (float*)wsb;              wsb += N_GRAPHS * 4;
    float*          out    = (float*)d_out;
    int2*           bedges = (int2*)agg;  // aliases agg; consumed in k_build before aggregate2

    // ---- CSR build (counting sort, fixed-capacity buckets, fused build)
    k_init<<<16, 256, 0, stream>>>(bcursor, pooled, cnt);
    k_binscatter<<<NCH, 256, 0, stream>>>(srcv, dstv, ew, bcursor, bedges);
    k_build<<<NB, 256, 0, stream>>>(bcursor, bedges, rowse, dis, csr);

    const int agg_blocks = (N_NODES + 4 * AGG_NPW - 1) / (4 * AGG_NPW);

    // ---- layer 1 (aggregate writes bf16 -> feeds gemm2 directly)
    k_gemm<IN_CH><<<(N_NODES + 63) / 64, 256, 0, stream>>>(x, W1, dis, hb);
    k_aggregate<true><<<agg_blocks, 256, 0, stream>>>(rowse, csr, (const uint2*)hb,
                                                      dis, b1, nullptr, (ushort4*)hbn);
    // ---- layer 2
    k_gemm2<<<(N_NODES + 63) / 64, 256, 0, stream>>>(hbn, W2, dis, hb);
    k_aggregate<false><<<agg_blocks, 256, 0, stream>>>(rowse, csr, (const uint2*)hb,
                                                       dis, b2, (float4*)agg, nullptr);

    // ---- pool + head
    k_pool<<<(N_NODES + POOL_NPB - 1) / POOL_NPB, 1024, 0, stream>>>(
        agg, batch, pooled, cnt);
    k_out<<<1, N_GRAPHS * N_CLASSES, 0, stream>>>(pooled, cnt, Wl, bl, out);
}

// Round 21
// 269.244 us; speedup vs baseline: 1.0442x; 1.0220x over previous
//
#include <hip/hip_runtime.h>
#include <hip/hip_fp16.h>

#define N_NODES   100000
#define N_EDGES   1600000
#define IN_CH     128
#define HID       64
#define N_CLASSES 16
#define N_GRAPHS  64

#define BK_SH     9                          // bucket = dst >> 9 (512 nodes/bucket)
#define BK_NODES  512
#define NB        ((N_NODES + BK_NODES - 1) / BK_NODES)   // 196 buckets
#define BK_CAP    10240                      // fixed bucket capacity (mean 8163, +23 sigma)
#define CH_EDGES  4096
#define EPT       16                         // edges/thread in binscatter (256 thr)
#define NCH       ((N_EDGES + CH_EDGES - 1) / CH_EDGES)   // 391 chunks
#define AGG_NPW   8                          // nodes per wave in aggregate

typedef __attribute__((ext_vector_type(8))) short bf16x8;
typedef __attribute__((ext_vector_type(4))) float f32x4;

__device__ __forceinline__ unsigned short f2bf(float f) {   // RNE f32->bf16
    unsigned u = __float_as_uint(f);
    u += 0x7fffu + ((u >> 16) & 1u);
    return (unsigned short)(u >> 16);
}
__device__ __forceinline__ float4 bf4(uint2 v) {            // 4 bf16 -> float4
    float4 o;
    o.x = __uint_as_float(v.x << 16);
    o.y = __uint_as_float(v.x & 0xffff0000u);
    o.z = __uint_as_float(v.y << 16);
    o.w = __uint_as_float(v.y & 0xffff0000u);
    return o;
}
// csr entry: src (17 bits) | fp16(ew) sign-free (15 bits) << 17
__device__ __forceinline__ float dec_ew(unsigned v) {
    return __half2float(__ushort_as_half((unsigned short)(v >> 17)));
}

// ---------------------------------------------------------------- init
__global__ void k_init(int* __restrict__ bcursor, float* __restrict__ pooled,
                       float* __restrict__ cnt) {
    int i = blockIdx.x * 256 + threadIdx.x;
    if (i < NB) bcursor[i] = i * BK_CAP;
    if (i < N_GRAPHS * HID) pooled[i] = 0.0f;
    if (i < N_GRAPHS) cnt[i] = 0.0f;
}

// ---------------------------------------------------------------- bin scatter (staged)
__global__ void k_binscatter(const int* __restrict__ src, const int* __restrict__ dst,
                             const float* __restrict__ ew, int* __restrict__ bcursor,
                             int2* __restrict__ bedges) {
    __shared__ int  hist[NB];
    __shared__ int  offs[NB];
    __shared__ int  gbase[NB];
    __shared__ int  sc[256];
    __shared__ int2 stage[CH_EDGES];
    __shared__ int  dest[CH_EDGES];
    const int t = threadIdx.x;
    const int base = blockIdx.x * CH_EDGES;
    const int nloc = min(CH_EDGES, N_EDGES - base);

    for (int i = t; i < NB; i += 256) hist[i] = 0;
    __syncthreads();

    int myb[EPT], myr[EPT], myp[EPT]; float myw[EPT];
#pragma unroll
    for (int j = 0; j < EPT; ++j) {
        int i = base + j * 256 + t;
        if (i < N_EDGES) {
            int s = src[i], d = dst[i];
            int b = d >> BK_SH;
            myb[j] = b;
            myr[j] = atomicAdd(&hist[b], 1);
            myp[j] = s | ((d & (BK_NODES - 1)) << 17);
            myw[j] = ew[i];
        } else {
            myb[j] = -1;
        }
    }
    __syncthreads();

    int v = (t < NB) ? hist[t] : 0;
    sc[t] = v;
    __syncthreads();
    for (int off = 1; off < 256; off <<= 1) {
        int a = (t >= off) ? sc[t - off] : 0;
        __syncthreads();
        sc[t] += a;
        __syncthreads();
    }
    if (t < NB) {
        offs[t] = sc[t] - v;
        gbase[t] = (v > 0) ? atomicAdd(&bcursor[t], v) : 0;
    }
    __syncthreads();

#pragma unroll
    for (int j = 0; j < EPT; ++j) {
        if (myb[j] >= 0) {
            int p = offs[myb[j]] + myr[j];
            stage[p] = make_int2(myp[j], __float_as_int(myw[j]));
            dest[p] = gbase[myb[j]] + myr[j];
        }
    }
    __syncthreads();

    for (int i = t; i < nloc; i += 256)
        bedges[dest[i]] = stage[i];
}

// ---------------------------------------------------------------- build (fused)
__global__ __launch_bounds__(256) void k_build(const int* __restrict__ bcursor,
                                               const int2* __restrict__ bedges,
                                               int2* __restrict__ rowse,
                                               float* __restrict__ dis,
                                               unsigned* __restrict__ csr) {
    __shared__ int2  eds[BK_CAP];         // 80 KB
    __shared__ int   cnt[BK_NODES];
    __shared__ float dsum[BK_NODES];
    __shared__ int   cur[BK_NODES];
    __shared__ int   sc[256];
    const int b = blockIdx.x;
    const int t = threadIdx.x;
    const int beg = b * BK_CAP, end = bcursor[b];
    const int n = end - beg;

    for (int i = t; i < BK_NODES; i += 256) { cnt[i] = 0; dsum[i] = 0.0f; }
    __syncthreads();

    for (int i = t; i < n; i += 256) {
        int2 e = bedges[beg + i];
        eds[i] = e;
        int dl = ((unsigned)e.x) >> 17;
        atomicAdd(&cnt[dl], 1);
        atomicAdd(&dsum[dl], __int_as_float(e.y));
    }
    __syncthreads();

    int a0 = cnt[2 * t], a1 = cnt[2 * t + 1];
    int pair = a0 + a1;
    sc[t] = pair;
    __syncthreads();
    for (int off = 1; off < 256; off <<= 1) {
        int a = (t >= off) ? sc[t - off] : 0;
        __syncthreads();
        sc[t] += a;
        __syncthreads();
    }
    int excl = sc[t] - pair;
    cur[2 * t] = excl;
    cur[2 * t + 1] = excl + a0;
    {
        int n0 = b * BK_NODES + 2 * t;
        if (n0 < N_NODES) {
            rowse[n0] = make_int2(beg + excl, beg + excl + a0);
            dis[n0] = rsqrtf(1.0f + dsum[2 * t]);
        }
        int n1 = n0 + 1;
        if (n1 < N_NODES) {
            rowse[n1] = make_int2(beg + excl + a0, beg + excl + a0 + a1);
            dis[n1] = rsqrtf(1.0f + dsum[2 * t + 1]);
        }
    }
    __syncthreads();

    for (int i = t; i < n; i += 256) {
        int2 e = eds[i];
        int dl = ((unsigned)e.x) >> 17;
        int s = e.x & 0x1FFFF;
        unsigned short w16 = __half_as_ushort(__float2half(__int_as_float(e.y)));
        int pos = beg + atomicAdd(&cur[dl], 1);
        csr[pos] = (unsigned)s | ((unsigned)w16 << 17);
    }
}

// ---------------------------------------------------------------- GEMM via MFMA (f32 input)
// Epilogue scales by dis[row]: hb = bf16(dis * (x@W))  [norm factoring]
template <int K>
__global__ __launch_bounds__(256) void k_gemm(const float* __restrict__ x,
                                              const float* __restrict__ W,
                                              const float* __restrict__ dis,
                                              unsigned short* __restrict__ hb) {
    constexpr int AS = K + 8;            // padded stride in bf16 elems
    __shared__ unsigned short a_s[64 * AS];   // a_s[row][k]
    __shared__ unsigned short wt[64 * AS];    // wt[n][k] = W[k][n]
    const int t    = threadIdx.x;
    const int lane = t & 63;
    const int wave = t >> 6;
    const int m    = lane & 15;
    const int quad = lane >> 4;
    const int rowbase = blockIdx.x * 64;

    constexpr int CPR = K / 8;
    for (int c = t; c < 64 * CPR; c += 256) {
        int row = c / CPR, cc = c % CPR;
        int gr = rowbase + row;
        float4 v0, v1;
        if (gr < N_NODES) {
            v0 = *(const float4*)&x[(long)gr * K + cc * 8];
            v1 = *(const float4*)&x[(long)gr * K + cc * 8 + 4];
        } else {
            v0 = make_float4(0.f, 0.f, 0.f, 0.f); v1 = v0;
        }
        uint4 p;
        p.x = f2bf(v0.x) | ((unsigned)f2bf(v0.y) << 16);
        p.y = f2bf(v0.z) | ((unsigned)f2bf(v0.w) << 16);
        p.z = f2bf(v1.x) | ((unsigned)f2bf(v1.y) << 16);
        p.w = f2bf(v1.z) | ((unsigned)f2bf(v1.w) << 16);
        *(uint4*)&a_s[row * AS + cc * 8] = p;
    }
    for (int idx = t; idx < K * 64; idx += 256) {
        int k = idx >> 6, n = idx & 63;
        wt[n * AS + k] = f2bf(W[idx]);
    }
    __syncthreads();

    bf16x8 bfrag[4][K / 32];
#pragma unroll
    for (int nt = 0; nt < 4; ++nt)
#pragma unroll
        for (int ks = 0; ks < K / 32; ++ks)
            bfrag[nt][ks] = *(const bf16x8*)&wt[(nt * 16 + m) * AS + ks * 32 + quad * 8];

    f32x4 acc[4];
#pragma unroll
    for (int nt = 0; nt < 4; ++nt) acc[nt] = (f32x4){0.f, 0.f, 0.f, 0.f};

#pragma unroll
    for (int ks = 0; ks < K / 32; ++ks) {
        bf16x8 af = *(const bf16x8*)&a_s[(wave * 16 + m) * AS + ks * 32 + quad * 8];
#pragma unroll
        for (int nt = 0; nt < 4; ++nt)
            acc[nt] = __builtin_amdgcn_mfma_f32_16x16x32_bf16(af, bfrag[nt][ks],
                                                              acc[nt], 0, 0, 0);
    }

#pragma unroll
    for (int i = 0; i < 4; ++i) {
        int gr = rowbase + wave * 16 + quad * 4 + i;
        if (gr < N_NODES) {
            float dsc = dis[gr];
#pragma unroll
            for (int nt = 0; nt < 4; ++nt)
                hb[(long)gr * HID + nt * 16 + m] = f2bf(dsc * acc[nt][i]);
        }
    }
}

// ---------------------------------------------------------------- aggregate (gather)
// Grid-stride: each wave handles AGG_NPW nodes; next node's rowse + self-row
// prefetched while current node's edge gathers are in flight.
__global__ void k_aggregate(const int2* __restrict__ rowse, const unsigned* __restrict__ csr,
                            const uint2* __restrict__ hb, const float* __restrict__ dis,
                            const float* __restrict__ b, float4* __restrict__ out4) {
    const int tid  = threadIdx.x;
    const int lane = tid & 63;
    const int g    = lane >> 4;          // edge group 0..3
    const int c4   = lane & 15;          // channel quad index
    const int nodebase = (blockIdx.x * 4 + (tid >> 6)) * AGG_NPW;
    const float4 bb = ((const float4*)b)[c4];

    if (nodebase >= N_NODES) return;

    int2 rs = rowse[nodebase];
    uint2 hsr = hb[nodebase * 16 + c4];

    for (int j = 0; j < AGG_NPW; ++j) {
        const int node = nodebase + j;
        if (node >= N_NODES) return;

        const int2 rs_c = rs;
        const float4 hs = bf4(hsr);
        if (j + 1 < AGG_NPW && node + 1 < N_NODES) {
            rs  = rowse[node + 1];
            hsr = hb[(node + 1) * 16 + c4];
        }

        float4 acc;
        if (g == 0) { acc = hs; }
        else        { acc.x = 0.f; acc.y = 0.f; acc.z = 0.f; acc.w = 0.f; }

        int p = rs_c.x;
        const int end = rs_c.y;

        unsigned d0, d1, d2, d3;
        if (p + 16 <= end) {
            d0 = csr[p + g];     d1 = csr[p + 4 + g];
            d2 = csr[p + 8 + g]; d3 = csr[p + 12 + g];
        }
        while (p + 16 <= end) {
            const unsigned e0 = d0, e1 = d1, e2 = d2, e3 = d3;
            const int pn = p + 16;
            if (pn + 16 <= end) {
                d0 = csr[pn + g];     d1 = csr[pn + 4 + g];
                d2 = csr[pn + 8 + g]; d3 = csr[pn + 12 + g];
            }
            float4 v0 = bf4(hb[(e0 & 0x1FFFF) * 16 + c4]);
            float4 v1 = bf4(hb[(e1 & 0x1FFFF) * 16 + c4]);
            float4 v2 = bf4(hb[(e2 & 0x1FFFF) * 16 + c4]);
            float4 v3 = bf4(hb[(e3 & 0x1FFFF) * 16 + c4]);
            float w0 = dec_ew(e0), w1 = dec_ew(e1);
            float w2 = dec_ew(e2), w3 = dec_ew(e3);
            acc.x += w0 * v0.x; acc.y += w0 * v0.y; acc.z += w0 * v0.z; acc.w += w0 * v0.w;
            acc.x += w1 * v1.x; acc.y += w1 * v1.y; acc.z += w1 * v1.z; acc.w += w1 * v1.w;
            acc.x += w2 * v2.x; acc.y += w2 * v2.y; acc.z += w2 * v2.z; acc.w += w2 * v2.w;
            acc.x += w3 * v3.x; acc.y += w3 * v3.y; acc.z += w3 * v3.z; acc.w += w3 * v3.w;
            p = pn;
        }
        if (p < end) {   // clamped tail block
            int i0 = p + g, i1 = p + 4 + g, i2 = p + 8 + g, i3 = p + 12 + g;
            unsigned e0 = csr[min(i0, end - 1)];
            unsigned e1 = csr[min(i1, end - 1)];
            unsigned e2 = csr[min(i2, end - 1)];
            unsigned e3 = csr[min(i3, end - 1)];
            float4 v0 = bf4(hb[(e0 & 0x1FFFF) * 16 + c4]);
            float4 v1 = bf4(hb[(e1 & 0x1FFFF) * 16 + c4]);
            float4 v2 = bf4(hb[(e2 & 0x1FFFF) * 16 + c4]);
            float4 v3 = bf4(hb[(e3 & 0x1FFFF) * 16 + c4]);
            float w0 = (i0 < end) ? dec_ew(e0) : 0.0f;
            float w1 = (i1 < end) ? dec_ew(e1) : 0.0f;
            float w2 = (i2 < end) ? dec_ew(e2) : 0.0f;
            float w3 = (i3 < end) ? dec_ew(e3) : 0.0f;
            acc.x += w0 * v0.x; acc.y += w0 * v0.y; acc.z += w0 * v0.z; acc.w += w0 * v0.w;
            acc.x += w1 * v1.x; acc.y += w1 * v1.y; acc.z += w1 * v1.z; acc.w += w1 * v1.w;
            acc.x += w2 * v2.x; acc.y += w2 * v2.y; acc.z += w2 * v2.z; acc.w += w2 * v2.w;
            acc.x += w3 * v3.x; acc.y += w3 * v3.y; acc.z += w3 * v3.z; acc.w += w3 * v3.w;
        }

        acc.x += __shfl_xor(acc.x, 16); acc.y += __shfl_xor(acc.y, 16);
        acc.z += __shfl_xor(acc.z, 16); acc.w += __shfl_xor(acc.w, 16);
        acc.x += __shfl_xor(acc.x, 32); acc.y += __shfl_xor(acc.y, 32);
        acc.z += __shfl_xor(acc.z, 32); acc.w += __shfl_xor(acc.w, 32);

        if (g == 0) {
            const float dd = dis[node];
            float4 o;
            o.x = fmaxf(dd * acc.x + bb.x, 0.0f);
            o.y = fmaxf(dd * acc.y + bb.y, 0.0f);
            o.z = fmaxf(dd * acc.z + bb.z, 0.0f);
            o.w = fmaxf(dd * acc.w + bb.w, 0.0f);
            out4[node * 16 + c4] = o;
        }
    }
}

// ---------------------------------------------------------------- pool (hierarchical)
#define POOL_NPB 256   // nodes per 1024-thread block
__global__ __launch_bounds__(1024) void k_pool(const float* __restrict__ agg,
                                               const int* __restrict__ batch,
                                               float* __restrict__ pooled,
                                               float* __restrict__ cnt) {
    __shared__ float psh[N_GRAPHS * HID];   // 16 KB
    __shared__ float csh[N_GRAPHS];
    const int tid = threadIdx.x;
    const int c = tid & 63;
    const int w = tid >> 6;                 // wave 0..15
    const int nodebase = blockIdx.x * POOL_NPB + w * 16;

    for (int i = tid; i < N_GRAPHS * HID; i += 1024) psh[i] = 0.f;
    if (tid < N_GRAPHS) csh[tid] = 0.f;
    __syncthreads();

    int curg = -1; float accv = 0.f, cntacc = 0.f;
    for (int j = 0; j < 16; ++j) {
        int node = nodebase + j;
        if (node >= N_NODES) break;
        int g = batch[node];                // wave-uniform
        float v = agg[node * HID + c];
        if (g != curg) {
            if (curg >= 0) {
                atomicAdd(&psh[curg * HID + c], accv);
                if (c == 0) atomicAdd(&csh[curg], cntacc);
            }
            curg = g; accv = 0.f; cntacc = 0.f;
        }
        accv += v; cntacc += 1.f;
    }
    if (curg >= 0) {
        atomicAdd(&psh[curg * HID + c], accv);
        if (c == 0) atomicAdd(&csh[curg], cntacc);
    }
    __syncthreads();

    for (int i = tid; i < N_GRAPHS * HID; i += 1024) {
        if (csh[i >> 6] > 0.f) atomicAdd(&pooled[i], psh[i]);
    }
    if (tid < N_GRAPHS && csh[tid] > 0.f) atomicAdd(&cnt[tid], csh[tid]);
}

// ---------------------------------------------------------------- head
__global__ void k_out(const float* __restrict__ pooled, const float* __restrict__ cnt,
                      const float* __restrict__ Wl, const float* __restrict__ bl,
                      float* __restrict__ out) {
    int tid = threadIdx.x;              // 1024 threads
    int g = tid >> 4, k = tid & 15;
    float inv = 1.0f / fmaxf(cnt[g], 1.0f);
    float acc = 0.f;
#pragma unroll
    for (int h = 0; h < HID; ++h) acc += pooled[g * HID + h] * Wl[h * N_CLASSES + k];
    out[g * N_CLASSES + k] = acc * inv + bl[k];
}

extern "C" void kernel_launch(void* const* d_in, const int* in_sizes, int n_in,
                              void* d_out, int out_size, void* d_ws, size_t ws_size,
                              hipStream_t stream) {
    const float* x     = (const float*)d_in[0];
    const int*   ei    = (const int*)d_in[1];
    const float* ew    = (const float*)d_in[2];
    const int*   batch = (const int*)d_in[3];
    const float* W1    = (const float*)d_in[4];
    const float* b1    = (const float*)d_in[5];
    const float* W2    = (const float*)d_in[6];
    const float* b2    = (const float*)d_in[7];
    const float* Wl    = (const float*)d_in[8];
    const float* bl    = (const float*)d_in[9];

    const int* srcv = ei;            // edge_index[0]
    const int* dstv = ei + N_EDGES;  // edge_index[1]

    // workspace layout (all offsets 16B-aligned)
    char* wsb = (char*)d_ws;
    float*          dis    = (float*)wsb;              wsb += 100352 * 4;
    int2*           rowse  = (int2*)wsb;               wsb += 100352 * 8;   // {beg,end}/node
    int*            bcursor= (int*)wsb;                wsb += 256 * 4;
    unsigned*       csr    = (unsigned*)wsb;           wsb += (size_t)NB * BK_CAP * 4;
    unsigned short* hb     = (unsigned short*)wsb;     wsb += N_NODES * HID * 2;  // bf16 dis*h
    float*          agg    = (float*)wsb;              wsb += N_NODES * HID * 4;
    float*          pooled = (float*)wsb;              wsb += N_GRAPHS * HID * 4;
    float*          cnt    = (float*)wsb;              wsb += N_GRAPHS * 4;
    float*          out    = (float*)d_out;
    int2*           bedges = (int2*)agg;  // aliases agg; consumed in k_build before aggregate1

    // ---- CSR build (counting sort, fixed-capacity buckets, fused build)
    k_init<<<16, 256, 0, stream>>>(bcursor, pooled, cnt);
    k_binscatter<<<NCH, 256, 0, stream>>>(srcv, dstv, ew, bcursor, bedges);
    k_build<<<NB, 256, 0, stream>>>(bcursor, bedges, rowse, dis, csr);

    const int agg_blocks = (N_NODES + 4 * AGG_NPW - 1) / (4 * AGG_NPW);

    // ---- layer 1
    k_gemm<IN_CH><<<(N_NODES + 63) / 64, 256, 0, stream>>>(x, W1, dis, hb);
    k_aggregate<<<agg_blocks, 256, 0, stream>>>(rowse, csr, (const uint2*)hb,
                                                dis, b1, (float4*)agg);
    // ---- layer 2
    k_gemm<HID><<<(N_NODES + 63) / 64, 256, 0, stream>>>(agg, W2, dis, hb);
    k_aggregate<<<agg_blocks, 256, 0, stream>>>(rowse, csr, (const uint2*)hb,
                                                dis, b2, (float4*)agg);

    // ---- pool + head
    k_pool<<<(N_NODES + POOL_NPB - 1) / POOL_NPB, 1024, 0, stream>>>(
        agg, batch, pooled, cnt);
    k_out<<<1, N_GRAPHS * N_CLASSES, 0, stream>>>(pooled, cnt, Wl, bl, out);
}